// Round 1
// baseline (7536.839 us; speedup 1.0000x reference)
//
#include <hip/hip_runtime.h>

#define NUu 100000
#define NIi 100000
#define NAa 10000
#define DD  64
#define NN0 (NUu + NIi)   // 200000
#define NN1 (NUu + NAa)   // 110000

// ---------------- kernels ----------------

// cur = acc = concat(a, b) ; na/ntot are float counts (multiples of 4)
__global__ void k_concat2(const float* __restrict__ a, const float* __restrict__ b,
                          long long na, long long ntot,
                          float* __restrict__ cur, float* __restrict__ acc) {
    long long i = ((long long)blockIdx.x * blockDim.x + threadIdx.x) * 4;
    if (i >= ntot) return;
    float4 v = (i < na) ? *(const float4*)(a + i) : *(const float4*)(b + (i - na));
    *(float4*)(cur + i) = v;
    *(float4*)(acc + i) = v;
}

// y[row[e]] += val[e] * x[col[e]]  — one wave per edge, lane = dim
__global__ void k_spmm(const int* __restrict__ rows, const int* __restrict__ cols,
                       const float* __restrict__ vals, const float* __restrict__ x,
                       float* __restrict__ y, int nedge) {
    long long idx = (long long)blockIdx.x * blockDim.x + threadIdx.x;
    int e = (int)(idx >> 6);
    if (e >= nedge) return;
    int d = (int)(idx & 63);
    int r = rows[e];
    int c = cols[e];
    float v = vals[e];
    atomicAdd(y + (((long long)r) << 6) + d, v * x[(((long long)c) << 6) + d]);
}

// acc += nxt  (float4 elements)
__global__ void k_add(float* __restrict__ acc, const float* __restrict__ nxt, long long n4) {
    long long i = (long long)blockIdx.x * blockDim.x + threadIdx.x;
    if (i >= n4) return;
    float4 a = ((const float4*)acc)[i];
    float4 b = ((const float4*)nxt)[i];
    a.x += b.x; a.y += b.y; a.z += b.z; a.w += b.w;
    ((float4*)acc)[i] = a;
}

// x *= s  (float4 elements)
__global__ void k_scale(float* __restrict__ x, float s, long long n4) {
    long long i = (long long)blockIdx.x * blockDim.x + threadIdx.x;
    if (i >= n4) return;
    float4 a = ((const float4*)x)[i];
    a.x *= s; a.y *= s; a.z *= s; a.w *= s;
    ((float4*)x)[i] = a;
}

// dst = src  (float4 elements)
__global__ void k_copy(float* __restrict__ dst, const float* __restrict__ src, long long n4) {
    long long i = (long long)blockIdx.x * blockDim.x + threadIdx.x;
    if (i >= n4) return;
    ((float4*)dst)[i] = ((const float4*)src)[i];
}

// in-place row L2-normalize, one 64-lane wave per row
__global__ void k_normalize(float* __restrict__ y, int nrows) {
    int r = blockIdx.x * (blockDim.x >> 6) + (threadIdx.x >> 6);
    if (r >= nrows) return;
    int d = threadIdx.x & 63;
    long long off = (((long long)r) << 6) + d;
    float v = y[off];
    float s = v * v;
    for (int m = 32; m; m >>= 1) s += __shfl_xor(s, m);
    float inv = 1.0f / fmaxf(sqrtf(s), 1e-12f);
    y[off] = v * inv;
}

// in-place: y = 0.5 * normalize(y) + 0.5 * base
__global__ void k_norm_blend(float* __restrict__ y, const float* __restrict__ base, int nrows) {
    int r = blockIdx.x * (blockDim.x >> 6) + (threadIdx.x >> 6);
    if (r >= nrows) return;
    int d = threadIdx.x & 63;
    long long off = (((long long)r) << 6) + d;
    float v = y[off];
    float s = v * v;
    for (int m = 32; m; m >>= 1) s += __shfl_xor(s, m);
    float inv = 1.0f / fmaxf(sqrtf(s), 1e-12f);
    y[off] = 0.5f * v * inv + 0.5f * base[off];
}

// ---------------- host ----------------

static inline int nblk(long long n, int b) { return (int)((n + b - 1) / b); }

extern "C" void kernel_launch(void* const* d_in, const int* in_sizes, int n_in,
                              void* d_out, int out_size, void* d_ws, size_t ws_size,
                              hipStream_t stream) {
    const float* emb_user   = (const float*)d_in[0];
    const float* emb_item   = (const float*)d_in[1];
    const float* emb_author = (const float*)d_in[2];
    const int*   g0r = (const int*)d_in[3];
    const int*   g0c = (const int*)d_in[4];
    const float* g0v = (const float*)d_in[5];
    const int*   g1r = (const int*)d_in[6];
    const int*   g1c = (const int*)d_in[7];
    const float* g1v = (const float*)d_in[8];
    const int*   g3r = (const int*)d_in[9];
    const int*   g3c = (const int*)d_in[10];
    const float* g3v = (const float*)d_in[11];
    const int*   g4r = (const int*)d_in[12];
    const int*   g4c = (const int*)d_in[13];
    const float* g4v = (const float*)d_in[14];
    const int*   g5r = (const int*)d_in[15];
    const int*   g5c = (const int*)d_in[16];
    const float* g5v = (const float*)d_in[17];

    const int E0 = in_sizes[3];
    const int E1 = in_sizes[6];
    const int E3 = in_sizes[9];
    const int E4 = in_sizes[12];
    const int E5 = in_sizes[15];

    float* out = (float*)d_out;

    // workspace carve-up (floats)
    float* acc0 = (float*)d_ws;                       // N0*64
    float* curA = acc0 + (long long)NN0 * DD;         // N0*64
    float* nxtA = curA + (long long)NN0 * DD;         // N0*64
    float* acc1 = nxtA + (long long)NN0 * DD;         // N1*64
    float* curB = acc1 + (long long)NN1 * DD;         // N1*64
    float* nxtB = curB + (long long)NN1 * DD;         // N1*64

    const int B = 256;
    const long long n0f = (long long)NN0 * DD;   // floats
    const long long n1f = (long long)NN1 * DD;

    // ---------- atom branch: propagate on g0 ----------
    k_concat2<<<nblk(n0f / 4, B), B, 0, stream>>>(emb_user, emb_item,
                                                  (long long)NUu * DD, n0f, curA, acc0);
    for (int l = 0; l < 3; ++l) {
        hipMemsetAsync(nxtA, 0, n0f * sizeof(float), stream);
        k_spmm<<<nblk((long long)E0 * 64, B), B, 0, stream>>>(g0r, g0c, g0v, curA, nxtA, E0);
        k_add<<<nblk(n0f / 4, B), B, 0, stream>>>(acc0, nxtA, n0f / 4);
        float* t = curA; curA = nxtA; nxtA = t;
    }
    k_scale<<<nblk(n0f / 4, B), B, 0, stream>>>(acc0, 0.25f, n0f / 4);
    // atom_users -> out rows [0, NU)
    k_copy<<<nblk((long long)NUu * DD / 4, B), B, 0, stream>>>(out, acc0, (long long)NUu * DD / 4);
    const float* items0 = acc0 + (long long)NUu * DD;   // atom_items0 [NI,64]

    // ---------- non-atom branch: propagate on g1 ----------
    k_concat2<<<nblk(n1f / 4, B), B, 0, stream>>>(emb_user, emb_author,
                                                  (long long)NUu * DD, n1f, curB, acc1);
    for (int l = 0; l < 3; ++l) {
        hipMemsetAsync(nxtB, 0, n1f * sizeof(float), stream);
        k_spmm<<<nblk((long long)E1 * 64, B), B, 0, stream>>>(g1r, g1c, g1v, curB, nxtB, E1);
        k_add<<<nblk(n1f / 4, B), B, 0, stream>>>(acc1, nxtB, n1f / 4);
        float* t = curB; curB = nxtB; nxtB = t;
    }
    k_scale<<<nblk(n1f / 4, B), B, 0, stream>>>(acc1, 0.25f, n1f / 4);
    // non_atom_users -> out rows [NU, 2NU)
    k_copy<<<nblk((long long)NUu * DD / 4, B), B, 0, stream>>>(out + (long long)NUu * DD, acc1,
                                                              (long long)NUu * DD / 4);
    const float* nau = acc1 + (long long)NUu * DD;      // non_atom_authors [NA,64]
    // non_atom_authors -> out rows [410000, 420000)
    k_copy<<<nblk((long long)NAa * DD / 4, B), B, 0, stream>>>(out + (long long)410000 * DD, nau,
                                                              (long long)NAa * DD / 4);

    // ---------- atom_authors = normalize(g3 @ items0), rows [400000, 410000) ----------
    float* oAuth = out + (long long)400000 * DD;
    hipMemsetAsync(oAuth, 0, (long long)NAa * DD * sizeof(float), stream);
    k_spmm<<<nblk((long long)E3 * 64, B), B, 0, stream>>>(g3r, g3c, g3v, items0, oAuth, E3);
    k_normalize<<<nblk(NAa, B / 64), B, 0, stream>>>(oAuth, NAa);

    // ---------- atom_items = 0.5*normalize(g5 @ items0) + 0.5*items0, rows [200000, 300000) ----------
    float* oItemA = out + (long long)200000 * DD;
    hipMemsetAsync(oItemA, 0, (long long)NIi * DD * sizeof(float), stream);
    k_spmm<<<nblk((long long)E5 * 64, B), B, 0, stream>>>(g5r, g5c, g5v, items0, oItemA, E5);
    k_norm_blend<<<nblk(NIi, B / 64), B, 0, stream>>>(oItemA, items0, NIi);

    // ---------- non_atom_items = normalize(g4 @ non_atom_authors), rows [300000, 400000) ----------
    float* oItemN = out + (long long)300000 * DD;
    hipMemsetAsync(oItemN, 0, (long long)NIi * DD * sizeof(float), stream);
    k_spmm<<<nblk((long long)E4 * 64, B), B, 0, stream>>>(g4r, g4c, g4v, nau, oItemN, E4);
    k_normalize<<<nblk(NIi, B / 64), B, 0, stream>>>(oItemN, NIi);
}

// Round 2
// 3049.836 us; speedup vs baseline: 2.4712x; 2.4712x over previous
//
#include <hip/hip_runtime.h>

#define NUu 100000
#define NIi 100000
#define NAa 10000
#define DD  64
#define NN0 (NUu + NIi)   // 200000
#define NN1 (NUu + NAa)   // 110000

// ---------------- CSR build kernels ----------------

__global__ void k_hist(const int* __restrict__ row, int* __restrict__ cnt, int E) {
    int e = blockIdx.x * blockDim.x + threadIdx.x;
    if (e >= E) return;
    atomicAdd(cnt + row[e], 1);
}

// per-block exclusive scan (256 elems/block), block sums out
__global__ void k_scan1(const int* __restrict__ cnt, int n,
                        int* __restrict__ excl, int* __restrict__ bsum) {
    __shared__ int s[256];
    int gid = blockIdx.x * 256 + threadIdx.x;
    int v = (gid < n) ? cnt[gid] : 0;
    s[threadIdx.x] = v;
    __syncthreads();
    for (int off = 1; off < 256; off <<= 1) {
        int t = (threadIdx.x >= off) ? s[threadIdx.x - off] : 0;
        __syncthreads();
        s[threadIdx.x] += t;
        __syncthreads();
    }
    if (gid < n) excl[gid] = s[threadIdx.x] - v;
    if (threadIdx.x == 255) bsum[blockIdx.x] = s[255];
}

// single-block exclusive scan of block sums (nb <= 1024)
__global__ void k_scan2(int* __restrict__ bsum, int nb) {
    __shared__ int s[1024];
    int v = (threadIdx.x < nb) ? bsum[threadIdx.x] : 0;
    s[threadIdx.x] = v;
    __syncthreads();
    for (int off = 1; off < 1024; off <<= 1) {
        int t = (threadIdx.x >= off) ? s[threadIdx.x - off] : 0;
        __syncthreads();
        s[threadIdx.x] += t;
        __syncthreads();
    }
    if (threadIdx.x < nb) bsum[threadIdx.x] = s[threadIdx.x] - v;
}

// combine -> row_ptr & cursor; also rp[n] = E
__global__ void k_scan3(const int* __restrict__ excl, const int* __restrict__ bsum,
                        int n, int E, int* __restrict__ rp, int* __restrict__ cur) {
    int gid = blockIdx.x * 256 + threadIdx.x;
    if (gid < n) {
        int v = excl[gid] + bsum[gid >> 8];
        rp[gid] = v;
        cur[gid] = v;
    }
    if (gid == n) rp[n] = E;
}

// ticketed scatter into interleaved {col, val_bits}
__global__ void k_scatter(const int* __restrict__ row, const int* __restrict__ col,
                          const float* __restrict__ val, int* __restrict__ cursor,
                          int2* __restrict__ spair, int E) {
    int e = blockIdx.x * blockDim.x + threadIdx.x;
    if (e >= E) return;
    int r = row[e];
    int pos = atomicAdd(cursor + r, 1);
    int2 p;
    p.x = col[e];
    p.y = __float_as_int(val[e]);
    spair[pos] = p;
}

// ---------------- SpMM (CSR gather, one wave per row, lane = dim) ----------------
// MODE 0: y = G@x, and acc (split into accU rows [0,split), accI rows [split,n)) += y
// MODE 1: y = normalize(G@x)
// MODE 2: y = 0.5*normalize(G@x) + 0.5*base
template <int MODE>
__global__ void k_spmm_csr(const int* __restrict__ rp, const int2* __restrict__ sp,
                           const float* __restrict__ x, float* __restrict__ y,
                           float* __restrict__ accU, float* __restrict__ accI,
                           const float* __restrict__ base, int split, int nrows) {
    int r = blockIdx.x * (blockDim.x >> 6) + (threadIdx.x >> 6);
    if (r >= nrows) return;
    int d = threadIdx.x & 63;
    int s = rp[r], e = rp[r + 1];
    float a = 0.f;
    int i = s;
    for (; i + 4 <= e; i += 4) {
        int2 p0 = sp[i], p1 = sp[i + 1], p2 = sp[i + 2], p3 = sp[i + 3];
        a += __int_as_float(p0.y) * x[(((long long)p0.x) << 6) + d];
        a += __int_as_float(p1.y) * x[(((long long)p1.x) << 6) + d];
        a += __int_as_float(p2.y) * x[(((long long)p2.x) << 6) + d];
        a += __int_as_float(p3.y) * x[(((long long)p3.x) << 6) + d];
    }
    for (; i < e; ++i) {
        int2 p = sp[i];
        a += __int_as_float(p.y) * x[(((long long)p.x) << 6) + d];
    }
    long long off = (((long long)r) << 6) + d;
    if (MODE == 0) {
        y[off] = a;
        if (r < split) accU[(((long long)r) << 6) + d] += a;
        else           accI[(((long long)(r - split)) << 6) + d] += a;
    } else {
        float sq = a * a;
        for (int m = 32; m; m >>= 1) sq += __shfl_xor(sq, m);
        float inv = 1.0f / fmaxf(sqrtf(sq), 1e-12f);
        if (MODE == 1) y[off] = a * inv;
        else           y[off] = 0.5f * a * inv + 0.5f * base[off];
    }
}

// ---------------- elementwise helpers ----------------

__global__ void k_copy(float* __restrict__ dst, const float* __restrict__ src, long long n4) {
    long long i = (long long)blockIdx.x * blockDim.x + threadIdx.x;
    if (i >= n4) return;
    ((float4*)dst)[i] = ((const float4*)src)[i];
}

__global__ void k_scale(float* __restrict__ x, float s, long long n4) {
    long long i = (long long)blockIdx.x * blockDim.x + threadIdx.x;
    if (i >= n4) return;
    float4 a = ((const float4*)x)[i];
    a.x *= s; a.y *= s; a.z *= s; a.w *= s;
    ((float4*)x)[i] = a;
}

// ---------------- host ----------------

static inline int nblk(long long n, int b) { return (int)((n + b - 1) / b); }
static inline size_t al256(size_t x) { return (x + 255) & ~(size_t)255; }

extern "C" void kernel_launch(void* const* d_in, const int* in_sizes, int n_in,
                              void* d_out, int out_size, void* d_ws, size_t ws_size,
                              hipStream_t stream) {
    const float* emb_user   = (const float*)d_in[0];
    const float* emb_item   = (const float*)d_in[1];
    const float* emb_author = (const float*)d_in[2];
    const int*   g0r = (const int*)d_in[3];
    const int*   g0c = (const int*)d_in[4];
    const float* g0v = (const float*)d_in[5];
    const int*   g1r = (const int*)d_in[6];
    const int*   g1c = (const int*)d_in[7];
    const float* g1v = (const float*)d_in[8];
    const int*   g3r = (const int*)d_in[9];
    const int*   g3c = (const int*)d_in[10];
    const float* g3v = (const float*)d_in[11];
    const int*   g4r = (const int*)d_in[12];
    const int*   g4c = (const int*)d_in[13];
    const float* g4v = (const float*)d_in[14];
    const int*   g5r = (const int*)d_in[15];
    const int*   g5c = (const int*)d_in[16];
    const float* g5v = (const float*)d_in[17];

    const int E0 = in_sizes[3];
    const int E1 = in_sizes[6];
    const int E3 = in_sizes[9];
    const int E4 = in_sizes[12];
    const int E5 = in_sizes[15];

    float* out = (float*)d_out;

    // ---- workspace carve-up ----
    char* w = (char*)d_ws;
    int*  rp     = (int*)w;  w += al256((size_t)(NN0 + 1) * 4);
    int*  cursor = (int*)w;  w += al256((size_t)NN0 * 4);
    int*  cnt    = (int*)w;  w += al256((size_t)NN0 * 4);
    int*  excl   = (int*)w;  w += al256((size_t)NN0 * 4);
    int*  bsum   = (int*)w;  w += al256((size_t)1024 * 4);
    int2* spair  = (int2*)w; w += al256((size_t)6400000 * 8);
    float* curb  = (float*)w; w += al256((size_t)NN0 * DD * 4);
    float* nxtb  = (float*)w; w += al256((size_t)NN0 * DD * 4);
    float* items0 = (float*)w; w += al256((size_t)NIi * DD * 4);

    const int B = 256;

    // CSR builder for one graph into the shared arena
    auto build_csr = [&](const int* row, const int* col, const float* val, int E, int N) {
        hipMemsetAsync(cnt, 0, (size_t)N * sizeof(int), stream);
        k_hist<<<nblk(E, B), B, 0, stream>>>(row, cnt, E);
        int nb = (N + 255) / 256;
        k_scan1<<<nb, 256, 0, stream>>>(cnt, N, excl, bsum);
        k_scan2<<<1, 1024, 0, stream>>>(bsum, nb);
        k_scan3<<<nblk(N + 1, 256), 256, 0, stream>>>(excl, bsum, N, E, rp, cursor);
        k_scatter<<<nblk(E, B), B, 0, stream>>>(row, col, val, cursor, spair, E);
    };

    const long long nuF = (long long)NUu * DD;   // 6.4M floats
    const long long niF = (long long)NIi * DD;
    const long long naF = (long long)NAa * DD;

    float* oUserA = out;                            // atom_users
    float* oUserN = out + nuF;                      // non_atom_users
    float* oItemA = out + (long long)200000 * DD;   // atom_items
    float* oItemN = out + (long long)300000 * DD;   // non_atom_items
    float* oAuthA = out + (long long)400000 * DD;   // atom_authors
    float* oAuthN = out + (long long)410000 * DD;   // non_atom_authors

    // ========== atom branch: 3-layer propagate on g0 ==========
    build_csr(g0r, g0c, g0v, E0, NN0);
    // acc init: users -> oUserA, items -> items0 ; cur = concat
    k_copy<<<nblk(nuF / 4, B), B, 0, stream>>>(oUserA, emb_user, nuF / 4);
    k_copy<<<nblk(niF / 4, B), B, 0, stream>>>(items0, emb_item, niF / 4);
    k_copy<<<nblk(nuF / 4, B), B, 0, stream>>>(curb, emb_user, nuF / 4);
    k_copy<<<nblk(niF / 4, B), B, 0, stream>>>(curb + nuF, emb_item, niF / 4);
    {
        float* cur = curb;
        float* nxt = nxtb;
        for (int l = 0; l < 3; ++l) {
            k_spmm_csr<0><<<nblk(NN0, 4), B, 0, stream>>>(rp, spair, cur, nxt,
                                                          oUserA, items0, nullptr, NUu, NN0);
            float* t = cur; cur = nxt; nxt = t;
        }
    }
    k_scale<<<nblk(nuF / 4, B), B, 0, stream>>>(oUserA, 0.25f, nuF / 4);
    k_scale<<<nblk(niF / 4, B), B, 0, stream>>>(items0, 0.25f, niF / 4);

    // ========== non-atom branch: 3-layer propagate on g1 ==========
    build_csr(g1r, g1c, g1v, E1, NN1);
    k_copy<<<nblk(nuF / 4, B), B, 0, stream>>>(oUserN, emb_user, nuF / 4);
    k_copy<<<nblk(naF / 4, B), B, 0, stream>>>(oAuthN, emb_author, naF / 4);
    k_copy<<<nblk(nuF / 4, B), B, 0, stream>>>(curb, emb_user, nuF / 4);
    k_copy<<<nblk(naF / 4, B), B, 0, stream>>>(curb + nuF, emb_author, naF / 4);
    {
        float* cur = curb;
        float* nxt = nxtb;
        for (int l = 0; l < 3; ++l) {
            k_spmm_csr<0><<<nblk(NN1, 4), B, 0, stream>>>(rp, spair, cur, nxt,
                                                          oUserN, oAuthN, nullptr, NUu, NN1);
            float* t = cur; cur = nxt; nxt = t;
        }
    }
    k_scale<<<nblk(nuF / 4, B), B, 0, stream>>>(oUserN, 0.25f, nuF / 4);
    k_scale<<<nblk(naF / 4, B), B, 0, stream>>>(oAuthN, 0.25f, naF / 4);

    // ========== atom_authors = normalize(g3 @ items0) ==========
    build_csr(g3r, g3c, g3v, E3, NAa);
    k_spmm_csr<1><<<nblk(NAa, 4), B, 0, stream>>>(rp, spair, items0, oAuthA,
                                                  nullptr, nullptr, nullptr, 0, NAa);

    // ========== atom_items = 0.5*normalize(g5 @ items0) + 0.5*items0 ==========
    build_csr(g5r, g5c, g5v, E5, NIi);
    k_spmm_csr<2><<<nblk(NIi, 4), B, 0, stream>>>(rp, spair, items0, oItemA,
                                                  nullptr, nullptr, items0, 0, NIi);

    // ========== non_atom_items = normalize(g4 @ non_atom_authors) ==========
    build_csr(g4r, g4c, g4v, E4, NIi);
    k_spmm_csr<1><<<nblk(NIi, 4), B, 0, stream>>>(rp, spair, oAuthN, oItemN,
                                                  nullptr, nullptr, nullptr, 0, NIi);
}